// Round 8
// baseline (338.572 us; speedup 1.0000x reference)
//
#include <hip/hip_runtime.h>
#include <hip/hip_bf16.h>

// B=2, L=2048, D=1024, H=16, Dh=64. fp32 in/out, int32 mask. ref = full-fp32 np.
//  K0 presplit: X,Wq,Wk -> (hi,lo) bf16; Wv -> bf16.
//  K1 qkv_gemm: 128x128 tile, 32 k-iters, 4-tensor staging in 32KB LDS, 48 MFMA/barrier
//     for Q/K (3-term split GEMM), 16 for V. V epilogue: LDS transpose + pk-bf16 stores.
//  K2 attn: ONLY Kh staged in LDS (dbuf, 1 barrier/iter); Kl, V, Q fragments direct
//     from global (contiguous 16B/lane; 4 waves share lines via L1). 24KB LDS ->
//     6 blocks/CU; ksplit=3 (1536 blocks, all co-resident). Bounded softmax
//     p = e^{30 tanh(x)-30} (fixed max) => partials combine by plain addition.
//  K3 combine: out = (o0+o1+o2)/(l0+l1+l2).
//  MFMA C-layout: row=quad*4+reg, col=lane&15 [m89/m91]; A/B-layout: [lane&15][quad*8+j] [m120].

typedef unsigned short u16;
typedef __bf16 bf16x8 __attribute__((ext_vector_type(8)));
typedef float f32x4 __attribute__((ext_vector_type(4)));

#define MFMA(a, b, c) __builtin_amdgcn_mfma_f32_16x16x32_bf16(a, b, c, 0, 0, 0)

__device__ __forceinline__ u16 bf16rne(float f) {
    unsigned int u = __float_as_uint(f);
    u += 0x7fffu + ((u >> 16) & 1u);
    return (u16)(u >> 16);
}
__device__ __forceinline__ float bf16f(u16 h) {
    return __uint_as_float(((unsigned int)h) << 16);
}
__device__ __forceinline__ void split1(float f, u16& hi, u16& lo) {
    hi = bf16rne(f);
    lo = bf16rne(f - bf16f(hi));
}
__device__ __forceinline__ unsigned int pk2(float a, float b) {   // v_cvt_pk_bf16_f32 (RNE)
    __hip_bfloat162 t = __float22bfloat162_rn(float2{a, b});
    return *(unsigned int*)&t;
}

// async global->LDS, 16B per lane. LDS dest must be uniform_base + lane*16.
__device__ __forceinline__ void gl16(const u16* g, u16* l) {
    __builtin_amdgcn_global_load_lds(
        (const __attribute__((address_space(1))) unsigned int*)g,
        (__attribute__((address_space(3))) unsigned int*)l, 16, 0, 0);
}

// ---------------- Kernel 0: pre-split fp32 -> bf16 hi/lo ----------------
__global__ __launch_bounds__(256) void presplit(
    const float* __restrict__ X, const float* __restrict__ Wq,
    const float* __restrict__ Wk, const float* __restrict__ Wv,
    u16* __restrict__ Xh, u16* __restrict__ Xl,
    u16* __restrict__ Wqh, u16* __restrict__ Wql,
    u16* __restrict__ Wkh, u16* __restrict__ Wkl,
    u16* __restrict__ Wvh)
{
    int i = blockIdx.x * 256 + threadIdx.x;
    const float* src; u16 *dh, *dl; int off;
    if (i < 1048576)      { src = X;  dh = Xh;  dl = Xl;      off = i; }
    else if (i < 1310720) { src = Wq; dh = Wqh; dl = Wql;     off = i - 1048576; }
    else if (i < 1572864) { src = Wk; dh = Wkh; dl = Wkl;     off = i - 1310720; }
    else                  { src = Wv; dh = Wvh; dl = nullptr; off = i - 1572864; }
    float4 v = ((const float4*)src)[off];
    ushort4 h, l;
    split1(v.x, h.x, l.x); split1(v.y, h.y, l.y);
    split1(v.z, h.z, l.z); split1(v.w, h.w, l.w);
    ((ushort4*)dh)[off] = h;
    if (dl) ((ushort4*)dl)[off] = l;
}

// ---------------- Kernel 1: QKV GEMM (4-tensor staging) ----------------
// 768 blocks; swizzle keeps all m-blocks of one n-block on one XCD.
__global__ __launch_bounds__(256, 4) void qkv_gemm(
    const u16* __restrict__ Xh, const u16* __restrict__ Xl,
    const u16* __restrict__ Wqh, const u16* __restrict__ Wql,
    const u16* __restrict__ Wkh, const u16* __restrict__ Wkl,
    const u16* __restrict__ Wvh,
    u16* __restrict__ Qh, u16* __restrict__ Ql,
    u16* __restrict__ Kh, u16* __restrict__ Kl,
    u16* __restrict__ VT)
{
    __shared__ __align__(16) u16 S[16384];    // staging 4x4096; epilogue transpose scratch
    u16* const Xhs = &S[0];
    u16* const Xls = &S[4096];
    u16* const Whs = &S[8192];
    u16* const Wls = &S[12288];
    const int tid = threadIdx.x;
    const int wave = tid >> 6, lane = tid & 63, quad = lane >> 4, c16 = lane & 15;
    const int id = blockIdx.x;
    const int nb = (((id >> 3) % 3) << 3) | (id & 7);   // 0..23
    const int m0 = ((id >> 3) / 3) * 128;
    const int mat = nb >> 3;
    const int n0 = (nb & 7) * 128;
    const u16* Bh = (mat == 0) ? Wqh : ((mat == 1) ? Wkh : Wvh);
    const u16* Bl = (mat == 0) ? Wql : Wkl;
    const int nseg = (mat < 2) ? 3 : 1;
    const int wm = (wave >> 1) * 64, wn = (wave & 1) * 64;

    const int srow0 = wave * 32 + (lane >> 2), scol = (lane & 3) * 8;

    f32x4 acc[4][4];
#pragma unroll
    for (int i = 0; i < 4; i++)
#pragma unroll
        for (int j = 0; j < 4; j++) acc[i][j] = (f32x4){0.f, 0.f, 0.f, 0.f};

    for (int kt = 0; kt < 32; kt++) {
        const int kcol = kt * 32;
#pragma unroll
        for (int s = 0; s < 2; s++) {
            int row = srow0 + s * 16;
            size_t go = (size_t)row * 1024 + kcol + scol;
            int lo = row * 32 + scol;
            gl16(Xh + (size_t)m0 * 1024 + go, &Xhs[lo]);
            gl16(Bh + (size_t)n0 * 1024 + go, &Whs[lo]);
            if (nseg == 3) {
                gl16(Xl + (size_t)m0 * 1024 + go, &Xls[lo]);
                gl16(Bl + (size_t)n0 * 1024 + go, &Wls[lo]);
            }
        }
        __syncthreads();
        for (int seg = 0; seg < nseg; seg++) {
            const u16* ap = (seg < 2) ? Xhs : Xls;
            const u16* bp = (seg == 1) ? Wls : Whs;
            bf16x8 af[4], bfr[4];
#pragma unroll
            for (int mt = 0; mt < 4; mt++)
                af[mt] = *(const bf16x8*)&ap[(wm + mt * 16 + c16) * 32 + quad * 8];
#pragma unroll
            for (int nt = 0; nt < 4; nt++)
                bfr[nt] = *(const bf16x8*)&bp[(wn + nt * 16 + c16) * 32 + quad * 8];
#pragma unroll
            for (int mt = 0; mt < 4; mt++)
#pragma unroll
                for (int nt = 0; nt < 4; nt++)
                    acc[mt][nt] = MFMA(af[mt], bfr[nt], acc[mt][nt]);
        }
        __syncthreads();
    }

    if (mat == 2) {
        // V epilogue: wave-private LDS transpose -> coalesced VT stores.
        u16* const T2 = &S[wave * 4096];
        const int nglob = n0 + wn + lane;
        const int hh = nglob >> 6, dh = nglob & 63;
        const int bh64 = ((m0 >> 11) * 16 + hh) * 64 + dh;
        u16* const vrow = VT + (size_t)bh64 * 2048 + (m0 & 2047) + wm;
#pragma unroll
        for (int half = 0; half < 2; half++) {
#pragma unroll
            for (int mt2 = 0; mt2 < 2; mt2++) {
                int mt = half * 2 + mt2;
#pragma unroll
                for (int nt = 0; nt < 4; nt++) {
                    uint2 d;
                    d.x = pk2(acc[mt][nt][0], acc[mt][nt][1]);
                    d.y = pk2(acc[mt][nt][2], acc[mt][nt][3]);
                    *(uint2*)&T2[(nt * 16 + c16) * 40 + mt2 * 16 + quad * 4] = d;
                }
            }
#pragma unroll
            for (int c = 0; c < 4; c++) {
                uint4 d = *(const uint4*)&T2[lane * 40 + c * 8];
                *(uint4*)&vrow[half * 32 + c * 8] = d;
            }
        }
    } else {
        const float scale = (mat == 0) ? 0.125f : 1.f;   // fold 1/sqrt(Dh) into Q (exact)
#pragma unroll
        for (int mt = 0; mt < 4; mt++) {
#pragma unroll
            for (int nt = 0; nt < 4; nt++) {
#pragma unroll
                for (int reg = 0; reg < 4; reg++) {
                    int mm = m0 + wm + mt * 16 + quad * 4 + reg;
                    int n = n0 + wn + nt * 16 + c16;
                    int b_ = mm >> 11, l = mm & 2047;
                    int h = n >> 6, dh = n & 63;
                    float v = acc[mt][nt][reg] * scale;
                    u16 hi, lo; split1(v, hi, lo);
                    int idx = ((b_ * 16 + h) * 2048 + l) * 64 + dh;
                    if (mat == 0) { Qh[idx] = hi; Ql[idx] = lo; }
                    else          { Kh[idx] = hi; Kl[idx] = lo; }
                }
            }
        }
    }
}

// ---------------- Kernel 2: flash attention, ksplit=3 ----------------
// grid (32 bh, 16 pair, 3 split) = 1536 blocks = 6/CU (24KB LDS). kb ≡ sp (mod 3).
__global__ __launch_bounds__(256, 6) void attn(
    const u16* __restrict__ Qh, const u16* __restrict__ Ql,
    const u16* __restrict__ Kh, const u16* __restrict__ Kl,
    const u16* __restrict__ VT, const int* __restrict__ AM,
    u16* __restrict__ Op, float* __restrict__ Lp)
{
    __shared__ __align__(16) u16 Khs[2][4096];
    __shared__ __align__(16) u16 Ps[4096];

    const int tid = threadIdx.x, wave = tid >> 6, lane = tid & 63;
    const int quad = lane >> 4, c16 = lane & 15;
    const int bh = blockIdx.x;                 // fast dim => bh pinned to an XCD
    const int pr = blockIdx.y;                 // 0..15
    const int sp = blockIdx.z;                 // ksplit part 0..2
    const int b_ = bh >> 4;
    const size_t base = (size_t)bh * 2048 * 64;

    const int swsub[2] = { (wave * 2) >> 2, (wave * 2 + 1) >> 2 };
    const int swrow[2] = { ((wave * 2) & 3) * 16 + (lane >> 2), ((wave * 2 + 1) & 3) * 16 + (lane >> 2) };
    const int scol = (lane & 3) * 8;

    auto stageK = [&](int k0, int buf) {
        const u16* Kht = Kh + base + (size_t)k0 * 64;
#pragma unroll
        for (int s = 0; s < 2; s++) {
            int sub = swsub[s], row = swrow[s];
            gl16(Kht + (size_t)row * 64 + sub * 32 + scol,
                 &Khs[buf][sub * 2048 + row * 32 + scol]);
        }
    };

    for (int tix = 0; tix < 2; ++tix) {
        const int qt = tix ? pr : 31 - pr;     // heavy tile first
        const int q0 = qt * 64;

        // Q fragments direct from global (A-layout rows contiguous: 16B/lane)
        const size_t qrow = base + (size_t)(q0 + wave * 16 + c16) * 64 + quad * 8;
        bf16x8 qh0 = *(const bf16x8*)&Qh[qrow];
        bf16x8 qh1 = *(const bf16x8*)&Qh[qrow + 32];
        bf16x8 ql0 = *(const bf16x8*)&Ql[qrow];
        bf16x8 ql1 = *(const bf16x8*)&Ql[qrow + 32];

        float rsl[4] = {0.f, 0.f, 0.f, 0.f};
        f32x4 o[4];
#pragma unroll
        for (int r = 0; r < 4; r++) o[r] = (f32x4){0.f, 0.f, 0.f, 0.f};

        if (sp <= qt) {
            stageK(sp * 64, 0);
            int cur = 0;
            for (int kb = sp; kb <= qt; kb += 3) {
                const int k0 = kb * 64;
                __syncthreads();                         // Khs[cur] landed; old reads done
                if (kb + 3 <= qt) stageK(k0 + 192, cur ^ 1);

                int mk[4];
#pragma unroll
                for (int nt = 0; nt < 4; nt++)
                    mk[nt] = AM[b_ * 2048 + k0 + nt * 16 + c16];
                const bool interior = (kb < qt);

                float p[4][4];
#pragma unroll
                for (int nt = 0; nt < 4; nt++) {
                    // Kl B-fragments direct from global (same pattern as Q; L1-shared)
                    const size_t krow = base + (size_t)(k0 + nt * 16 + c16) * 64 + quad * 8;
                    bf16x8 kl0 = *(const bf16x8*)&Kl[krow];
                    bf16x8 kl1 = *(const bf16x8*)&Kl[krow + 32];
                    bf16x8 kh0 = *(const bf16x8*)&Khs[cur][(nt * 16 + c16) * 32 + quad * 8];
                    bf16x8 kh1 = *(const bf16x8*)&Khs[cur][2048 + (nt * 16 + c16) * 32 + quad * 8];
                    f32x4 sa = (f32x4){0.f, 0.f, 0.f, 0.f};
                    sa = MFMA(qh0, kh0, sa);
                    sa = MFMA(qh1, kh1, sa);
                    sa = MFMA(ql0, kh0, sa);
                    sa = MFMA(ql1, kh1, sa);
                    sa = MFMA(qh0, kl0, sa);
                    sa = MFMA(qh1, kl1, sa);
                    const int key = k0 + nt * 16 + c16;
                    const bool mok = (mk[nt] != 0);
#pragma unroll
                    for (int reg = 0; reg < 4; reg++) {
                        int qg = q0 + wave * 16 + quad * 4 + reg;
                        float x = sa[reg];                       // pre-scaled by 1/8 via Q
                        float e1 = __expf(2.f * x);              // inf-safe (p->1)
                        float r  = __builtin_amdgcn_rcpf(e1 + 1.f);
                        float pv = __expf(-60.f * r);            // e^{30 tanh(x)-30}
                        bool keep = mok && (interior || key <= qg);
                        pv = keep ? pv : 0.f;
                        p[nt][reg] = pv;
                        rsl[reg] += pv;
                    }
                }

                // P: C-layout -> A-layout via wave-private LDS rows (in-order DS pipe)
#pragma unroll
                for (int nt = 0; nt < 4; nt++) {
                    int kl_ = nt * 16 + c16, sub = kl_ >> 5, kc = kl_ & 31;
#pragma unroll
                    for (int reg = 0; reg < 4; reg++)
                        Ps[sub * 2048 + (wave * 16 + quad * 4 + reg) * 32 + kc] = bf16rne(p[nt][reg]);
                }
                bf16x8 p0 = *(const bf16x8*)&Ps[(wave * 16 + c16) * 32 + quad * 8];
                bf16x8 p1 = *(const bf16x8*)&Ps[2048 + (wave * 16 + c16) * 32 + quad * 8];

                // V fragments direct from VT (B-layout rows contiguous; L1-shared)
#pragma unroll
                for (int dt = 0; dt < 4; dt++) {
                    const size_t vrow = (size_t)(bh * 64 + dt * 16 + c16) * 2048 + k0 + quad * 8;
                    bf16x8 v0 = *(const bf16x8*)&VT[vrow];
                    bf16x8 v1 = *(const bf16x8*)&VT[vrow + 32];
                    o[dt] = MFMA(p0, v0, o[dt]);
                    o[dt] = MFMA(p1, v1, o[dt]);
                }
                cur ^= 1;
            }
        }
        __syncthreads();   // all Khs reads done before next tile's staging reuses buf 0

        // partial epilogue: o (bf16) and l (f32) per (sp, bh, qt)
        const size_t obase = (((size_t)sp * 1024 + (size_t)bh * 32 + qt) * 4096);
        const size_t lbase = (((size_t)sp * 1024 + (size_t)bh * 32 + qt) * 64);
        float lsum[4];
#pragma unroll
        for (int reg = 0; reg < 4; reg++) {
            float v = rsl[reg];
#pragma unroll
            for (int off = 1; off < 16; off <<= 1)
                v += __shfl_xor(v, off);
            lsum[reg] = v;
        }
        if (c16 == 0) {
#pragma unroll
            for (int reg = 0; reg < 4; reg++)
                Lp[lbase + wave * 16 + quad * 4 + reg] = lsum[reg];
        }
#pragma unroll
        for (int dt = 0; dt < 4; dt++)
#pragma unroll
            for (int reg = 0; reg < 4; reg++) {
                int row = wave * 16 + quad * 4 + reg;
                int d = dt * 16 + c16;
                Op[obase + row * 64 + d] = bf16rne(o[dt][reg]);
            }
    }
}

// ---------------- Kernel 3: combine ksplit partials ----------------
__global__ __launch_bounds__(256) void combine(
    const u16* __restrict__ Op, const float* __restrict__ Lp,
    float* __restrict__ Out)
{
    const int i = blockIdx.x * 256 + threadIdx.x;   // 1048576 threads, 4 floats each
    const size_t lin = (size_t)i * 4;
    const int d  = (int)(lin & 1023);
    const int h  = d >> 6, dd = d & 63;
    const int l  = (int)((lin >> 10) & 2047);
    const int b  = (int)(lin >> 21);
    const int qt = l >> 6, row = l & 63;
    const int bh = b * 16 + h;
    const size_t o0 = (((size_t)bh * 32 + qt) * 4096) + row * 64 + dd;
    const size_t l0 = (((size_t)bh * 32 + qt) * 64) + row;
    const size_t OS = (size_t)1024 * 4096;
    ushort4 pa = *(const ushort4*)&Op[o0];
    ushort4 pb = *(const ushort4*)&Op[o0 + OS];
    ushort4 pc = *(const ushort4*)&Op[o0 + 2 * OS];
    float inv = __builtin_amdgcn_rcpf(Lp[l0] + Lp[l0 + 65536] + Lp[l0 + 131072]);
    float4 r;
    r.x = (bf16f(pa.x) + bf16f(pb.x) + bf16f(pc.x)) * inv;
    r.y = (bf16f(pa.y) + bf16f(pb.y) + bf16f(pc.y)) * inv;
    r.z = (bf16f(pa.z) + bf16f(pb.z) + bf16f(pc.z)) * inv;
    r.w = (bf16f(pa.w) + bf16f(pb.w) + bf16f(pc.w)) * inv;
    *(float4*)&Out[lin] = r;
}

extern "C" void kernel_launch(void* const* d_in, const int* in_sizes, int n_in,
                              void* d_out, int out_size, void* d_ws, size_t ws_size,
                              hipStream_t stream) {
    const float* X  = (const float*)d_in[0];
    const int*   AM = (const int*)d_in[1];
    const float* Wq = (const float*)d_in[2];
    const float* Wk = (const float*)d_in[3];
    const float* Wv = (const float*)d_in[4];
    float* out = (float*)d_out;

    const size_t NE = (size_t)2 * 16 * 2048 * 64;   // 4.19M elems
    const size_t WN = (size_t)1024 * 1024;
    u16* Qh  = (u16*)d_ws;
    u16* Ql  = Qh + NE;
    u16* Kh  = Ql + NE;
    u16* Kl  = Kh + NE;
    u16* VT  = Kl + NE;
    u16* Xh  = VT + NE;      // Xh..Wkl dead after qkv_gemm -> reused as Op (12.6M u16)
    u16* Xl  = Xh + NE;
    u16* Wqh = Xl + NE;
    u16* Wql = Wqh + WN;
    u16* Wkh = Wql + WN;
    u16* Wkl = Wkh + WN;
    u16* Wvh = Wkl + WN;     // dead after qkv_gemm -> reused as Lp (196K f32)
    u16*   Op = Xh;
    float* Lp = (float*)Wvh;

    presplit<<<7168, 256, 0, stream>>>(X, Wq, Wk, Wv, Xh, Xl, Wqh, Wql, Wkh, Wkl, Wvh);
    qkv_gemm<<<768, 256, 0, stream>>>(Xh, Xl, Wqh, Wql, Wkh, Wkl, Wvh,
                                      Qh, Ql, Kh, Kl, VT);
    attn<<<dim3(32, 16, 3), 256, 0, stream>>>(Qh, Ql, Kh, Kl, VT, AM, Op, Lp);
    combine<<<4096, 256, 0, stream>>>(Op, Lp, out);
}

// Round 9
// 241.080 us; speedup vs baseline: 1.4044x; 1.4044x over previous
//
#include <hip/hip_runtime.h>
#include <hip/hip_bf16.h>

// B=2, L=2048, D=1024, H=16, Dh=64. fp32 in/out, int32 mask. ref = full-fp32 np.
//  K0 presplit: X,Wq,Wk -> (hi,lo) bf16; Wv -> bf16.
//  K1 qkv_gemm: 128x128 tile, 32 k-iters, 4-tensor staging in 32KB LDS, 48 MFMA/barrier
//     for Q/K (3-term split GEMM), 16 for V. V epilogue: LDS transpose + pk-bf16 stores.
//     Q scaled by 2*log2e/8 (exp2 folding for attn softmax).
//  K2 attn (R7 structure -- R8's Kl-direct + ksplit=3 thrashed L2, FETCH 6x):
//     Kh+Kl staged in LDS dbuf (1 barrier/iter), V+Q direct from global, ksplit=2,
//     40KB LDS = 4 blocks/CU. Bounded softmax p = e^{30 tanh(x)-30} via exp2:
//     u=exp2(sa); p=exp2(-86.5617*rcp(u+1)). Interior blocks skip causal compares.
//  K3 combine: out = (o0+o1)/(l0+l1).
//  MFMA C-layout: row=quad*4+reg, col=lane&15 [m89/m91]; A/B-layout: [lane&15][quad*8+j] [m120].

typedef unsigned short u16;
typedef __bf16 bf16x8 __attribute__((ext_vector_type(8)));
typedef float f32x4 __attribute__((ext_vector_type(4)));

#define MFMA(a, b, c) __builtin_amdgcn_mfma_f32_16x16x32_bf16(a, b, c, 0, 0, 0)

__device__ __forceinline__ u16 bf16rne(float f) {
    unsigned int u = __float_as_uint(f);
    u += 0x7fffu + ((u >> 16) & 1u);
    return (u16)(u >> 16);
}
__device__ __forceinline__ float bf16f(u16 h) {
    return __uint_as_float(((unsigned int)h) << 16);
}
__device__ __forceinline__ void split1(float f, u16& hi, u16& lo) {
    hi = bf16rne(f);
    lo = bf16rne(f - bf16f(hi));
}
__device__ __forceinline__ unsigned int pk2(float a, float b) {   // v_cvt_pk_bf16_f32 (RNE)
    __hip_bfloat162 t = __float22bfloat162_rn(float2{a, b});
    return *(unsigned int*)&t;
}

// async global->LDS, 16B per lane. LDS dest must be uniform_base + lane*16.
__device__ __forceinline__ void gl16(const u16* g, u16* l) {
    __builtin_amdgcn_global_load_lds(
        (const __attribute__((address_space(1))) unsigned int*)g,
        (__attribute__((address_space(3))) unsigned int*)l, 16, 0, 0);
}

// ---------------- Kernel 0: pre-split fp32 -> bf16 hi/lo ----------------
__global__ __launch_bounds__(256) void presplit(
    const float* __restrict__ X, const float* __restrict__ Wq,
    const float* __restrict__ Wk, const float* __restrict__ Wv,
    u16* __restrict__ Xh, u16* __restrict__ Xl,
    u16* __restrict__ Wqh, u16* __restrict__ Wql,
    u16* __restrict__ Wkh, u16* __restrict__ Wkl,
    u16* __restrict__ Wvh)
{
    int i = blockIdx.x * 256 + threadIdx.x;
    const float* src; u16 *dh, *dl; int off;
    if (i < 1048576)      { src = X;  dh = Xh;  dl = Xl;      off = i; }
    else if (i < 1310720) { src = Wq; dh = Wqh; dl = Wql;     off = i - 1048576; }
    else if (i < 1572864) { src = Wk; dh = Wkh; dl = Wkl;     off = i - 1310720; }
    else                  { src = Wv; dh = Wvh; dl = nullptr; off = i - 1572864; }
    float4 v = ((const float4*)src)[off];
    ushort4 h, l;
    split1(v.x, h.x, l.x); split1(v.y, h.y, l.y);
    split1(v.z, h.z, l.z); split1(v.w, h.w, l.w);
    ((ushort4*)dh)[off] = h;
    if (dl) ((ushort4*)dl)[off] = l;
}

// ---------------- Kernel 1: QKV GEMM (4-tensor staging) ----------------
// 768 blocks; swizzle keeps all m-blocks of one n-block on one XCD.
__global__ __launch_bounds__(256, 4) void qkv_gemm(
    const u16* __restrict__ Xh, const u16* __restrict__ Xl,
    const u16* __restrict__ Wqh, const u16* __restrict__ Wql,
    const u16* __restrict__ Wkh, const u16* __restrict__ Wkl,
    const u16* __restrict__ Wvh,
    u16* __restrict__ Qh, u16* __restrict__ Ql,
    u16* __restrict__ Kh, u16* __restrict__ Kl,
    u16* __restrict__ VT)
{
    __shared__ __align__(16) u16 S[16384];    // staging 4x4096; epilogue transpose scratch
    u16* const Xhs = &S[0];
    u16* const Xls = &S[4096];
    u16* const Whs = &S[8192];
    u16* const Wls = &S[12288];
    const int tid = threadIdx.x;
    const int wave = tid >> 6, lane = tid & 63, quad = lane >> 4, c16 = lane & 15;
    const int id = blockIdx.x;
    const int nb = (((id >> 3) % 3) << 3) | (id & 7);   // 0..23
    const int m0 = ((id >> 3) / 3) * 128;
    const int mat = nb >> 3;
    const int n0 = (nb & 7) * 128;
    const u16* Bh = (mat == 0) ? Wqh : ((mat == 1) ? Wkh : Wvh);
    const u16* Bl = (mat == 0) ? Wql : Wkl;
    const int nseg = (mat < 2) ? 3 : 1;
    const int wm = (wave >> 1) * 64, wn = (wave & 1) * 64;

    const int srow0 = wave * 32 + (lane >> 2), scol = (lane & 3) * 8;

    f32x4 acc[4][4];
#pragma unroll
    for (int i = 0; i < 4; i++)
#pragma unroll
        for (int j = 0; j < 4; j++) acc[i][j] = (f32x4){0.f, 0.f, 0.f, 0.f};

    for (int kt = 0; kt < 32; kt++) {
        const int kcol = kt * 32;
#pragma unroll
        for (int s = 0; s < 2; s++) {
            int row = srow0 + s * 16;
            size_t go = (size_t)row * 1024 + kcol + scol;
            int lo = row * 32 + scol;
            gl16(Xh + (size_t)m0 * 1024 + go, &Xhs[lo]);
            gl16(Bh + (size_t)n0 * 1024 + go, &Whs[lo]);
            if (nseg == 3) {
                gl16(Xl + (size_t)m0 * 1024 + go, &Xls[lo]);
                gl16(Bl + (size_t)n0 * 1024 + go, &Wls[lo]);
            }
        }
        __syncthreads();
        for (int seg = 0; seg < nseg; seg++) {
            const u16* ap = (seg < 2) ? Xhs : Xls;
            const u16* bp = (seg == 1) ? Wls : Whs;
            bf16x8 af[4], bfr[4];
#pragma unroll
            for (int mt = 0; mt < 4; mt++)
                af[mt] = *(const bf16x8*)&ap[(wm + mt * 16 + c16) * 32 + quad * 8];
#pragma unroll
            for (int nt = 0; nt < 4; nt++)
                bfr[nt] = *(const bf16x8*)&bp[(wn + nt * 16 + c16) * 32 + quad * 8];
#pragma unroll
            for (int mt = 0; mt < 4; mt++)
#pragma unroll
                for (int nt = 0; nt < 4; nt++)
                    acc[mt][nt] = MFMA(af[mt], bfr[nt], acc[mt][nt]);
        }
        __syncthreads();
    }

    if (mat == 2) {
        // V epilogue: wave-private LDS transpose -> coalesced VT stores.
        u16* const T2 = &S[wave * 4096];
        const int nglob = n0 + wn + lane;
        const int hh = nglob >> 6, dh = nglob & 63;
        const int bh64 = ((m0 >> 11) * 16 + hh) * 64 + dh;
        u16* const vrow = VT + (size_t)bh64 * 2048 + (m0 & 2047) + wm;
#pragma unroll
        for (int half = 0; half < 2; half++) {
#pragma unroll
            for (int mt2 = 0; mt2 < 2; mt2++) {
                int mt = half * 2 + mt2;
#pragma unroll
                for (int nt = 0; nt < 4; nt++) {
                    uint2 d;
                    d.x = pk2(acc[mt][nt][0], acc[mt][nt][1]);
                    d.y = pk2(acc[mt][nt][2], acc[mt][nt][3]);
                    *(uint2*)&T2[(nt * 16 + c16) * 40 + mt2 * 16 + quad * 4] = d;
                }
            }
#pragma unroll
            for (int c = 0; c < 4; c++) {
                uint4 d = *(const uint4*)&T2[lane * 40 + c * 8];
                *(uint4*)&vrow[half * 32 + c * 8] = d;
            }
        }
    } else {
        // Q scale folds 1/sqrt(Dh) AND 2*log2e (softmax exp2 folding): 0.25*log2(e)
        const float scale = (mat == 0) ? 0.36067376022224085f : 1.f;
#pragma unroll
        for (int mt = 0; mt < 4; mt++) {
#pragma unroll
            for (int nt = 0; nt < 4; nt++) {
#pragma unroll
                for (int reg = 0; reg < 4; reg++) {
                    int mm = m0 + wm + mt * 16 + quad * 4 + reg;
                    int n = n0 + wn + nt * 16 + c16;
                    int b_ = mm >> 11, l = mm & 2047;
                    int h = n >> 6, dh = n & 63;
                    float v = acc[mt][nt][reg] * scale;
                    u16 hi, lo; split1(v, hi, lo);
                    int idx = ((b_ * 16 + h) * 2048 + l) * 64 + dh;
                    if (mat == 0) { Qh[idx] = hi; Ql[idx] = lo; }
                    else          { Kh[idx] = hi; Kl[idx] = lo; }
                }
            }
        }
    }
}

// ---------------- Kernel 2: flash attention, ksplit=2 (R7 structure) ----------------
// grid (32 bh, 16 pair, 2 split). Block: q-tiles {31-p, p}, k-blocks kb≡sp (mod 2).
__global__ __launch_bounds__(256, 4) void attn(
    const u16* __restrict__ Qh, const u16* __restrict__ Ql,
    const u16* __restrict__ Kh, const u16* __restrict__ Kl,
    const u16* __restrict__ VT, const int* __restrict__ AM,
    u16* __restrict__ Op, float* __restrict__ Lp)
{
    __shared__ __align__(16) u16 Khs[2][4096];
    __shared__ __align__(16) u16 Kls[2][4096];
    __shared__ __align__(16) u16 Ps[4096];

    const int tid = threadIdx.x, wave = tid >> 6, lane = tid & 63;
    const int quad = lane >> 4, c16 = lane & 15;
    const int bh = blockIdx.x;                 // fast dim => bh pinned to an XCD
    const int pr = blockIdx.y;                 // 0..15
    const int sp = blockIdx.z;                 // ksplit part 0/1
    const int b_ = bh >> 4;
    const size_t base = (size_t)bh * 2048 * 64;

    const int swsub[2] = { (wave * 2) >> 2, (wave * 2 + 1) >> 2 };
    const int swrow[2] = { ((wave * 2) & 3) * 16 + (lane >> 2), ((wave * 2 + 1) & 3) * 16 + (lane >> 2) };
    const int scol = (lane & 3) * 8;

    auto stageK = [&](int k0, int buf) {
        const u16* Kht = Kh + base + (size_t)k0 * 64;
        const u16* Klt = Kl + base + (size_t)k0 * 64;
#pragma unroll
        for (int s = 0; s < 2; s++) {
            int sub = swsub[s], row = swrow[s];
            int lo = sub * 2048 + row * 32 + scol;
            gl16(Kht + (size_t)row * 64 + sub * 32 + scol, &Khs[buf][lo]);
            gl16(Klt + (size_t)row * 64 + sub * 32 + scol, &Kls[buf][lo]);
        }
    };

    for (int tix = 0; tix < 2; ++tix) {
        const int qt = tix ? pr : 31 - pr;     // heavy tile first
        const int q0 = qt * 64;

        // Q fragments direct from global (A-layout rows contiguous: 16B/lane)
        const size_t qrow = base + (size_t)(q0 + wave * 16 + c16) * 64 + quad * 8;
        bf16x8 qh0 = *(const bf16x8*)&Qh[qrow];
        bf16x8 qh1 = *(const bf16x8*)&Qh[qrow + 32];
        bf16x8 ql0 = *(const bf16x8*)&Ql[qrow];
        bf16x8 ql1 = *(const bf16x8*)&Ql[qrow + 32];

        float rsl[4] = {0.f, 0.f, 0.f, 0.f};
        f32x4 o[4];
#pragma unroll
        for (int r = 0; r < 4; r++) o[r] = (f32x4){0.f, 0.f, 0.f, 0.f};

        if (sp <= qt) {
            stageK(sp * 64, 0);
            int cur = 0;
            for (int kb = sp; kb <= qt; kb += 2) {
                const int k0 = kb * 64;
                __syncthreads();                         // Khs[cur] landed; old reads done
                if (kb + 2 <= qt) stageK(k0 + 128, cur ^ 1);

                int mk[4];
#pragma unroll
                for (int nt = 0; nt < 4; nt++)
                    mk[nt] = AM[b_ * 2048 + k0 + nt * 16 + c16];
                const bool interior = (kb < qt);

                float p[4][4];
#pragma unroll
                for (int nt = 0; nt < 4; nt++) {
                    bf16x8 kh0 = *(const bf16x8*)&Khs[cur][(nt * 16 + c16) * 32 + quad * 8];
                    bf16x8 kh1 = *(const bf16x8*)&Khs[cur][2048 + (nt * 16 + c16) * 32 + quad * 8];
                    bf16x8 kl0 = *(const bf16x8*)&Kls[cur][(nt * 16 + c16) * 32 + quad * 8];
                    bf16x8 kl1 = *(const bf16x8*)&Kls[cur][2048 + (nt * 16 + c16) * 32 + quad * 8];
                    f32x4 sa = (f32x4){0.f, 0.f, 0.f, 0.f};
                    sa = MFMA(qh0, kh0, sa);
                    sa = MFMA(qh1, kh1, sa);
                    sa = MFMA(ql0, kh0, sa);
                    sa = MFMA(ql1, kh1, sa);
                    sa = MFMA(qh0, kl0, sa);
                    sa = MFMA(qh1, kl1, sa);
                    const bool mok = (mk[nt] != 0);
                    if (interior) {
#pragma unroll
                        for (int reg = 0; reg < 4; reg++) {
                            // sa pre-scaled by 2*log2e/8: u = e^{2x}
                            float u  = __builtin_exp2f(sa[reg]);
                            float r  = __builtin_amdgcn_rcpf(u + 1.f);
                            float pv = __builtin_exp2f(-86.5617024533378f * r);  // e^{30tanh-30}
                            pv = mok ? pv : 0.f;
                            p[nt][reg] = pv;
                            rsl[reg] += pv;
                        }
                    } else {
                        const int key = k0 + nt * 16 + c16;
#pragma unroll
                        for (int reg = 0; reg < 4; reg++) {
                            int qg = q0 + wave * 16 + quad * 4 + reg;
                            float u  = __builtin_exp2f(sa[reg]);
                            float r  = __builtin_amdgcn_rcpf(u + 1.f);
                            float pv = __builtin_exp2f(-86.5617024533378f * r);
                            bool keep = mok && (key <= qg);
                            pv = keep ? pv : 0.f;
                            p[nt][reg] = pv;
                            rsl[reg] += pv;
                        }
                    }
                }

                // P: C-layout -> A-layout via wave-private LDS rows (in-order DS pipe)
#pragma unroll
                for (int nt = 0; nt < 4; nt++) {
                    int kl_ = nt * 16 + c16, sub = kl_ >> 5, kc = kl_ & 31;
#pragma unroll
                    for (int reg = 0; reg < 4; reg++)
                        Ps[sub * 2048 + (wave * 16 + quad * 4 + reg) * 32 + kc] = bf16rne(p[nt][reg]);
                }
                bf16x8 p0 = *(const bf16x8*)&Ps[(wave * 16 + c16) * 32 + quad * 8];
                bf16x8 p1 = *(const bf16x8*)&Ps[2048 + (wave * 16 + c16) * 32 + quad * 8];

                // V fragments direct from VT (B-layout rows contiguous; L1-shared)
#pragma unroll
                for (int dt = 0; dt < 4; dt++) {
                    const size_t vrow = (size_t)(bh * 64 + dt * 16 + c16) * 2048 + k0 + quad * 8;
                    bf16x8 v0 = *(const bf16x8*)&VT[vrow];
                    bf16x8 v1 = *(const bf16x8*)&VT[vrow + 32];
                    o[dt] = MFMA(p0, v0, o[dt]);
                    o[dt] = MFMA(p1, v1, o[dt]);
                }
                cur ^= 1;
            }
        }
        __syncthreads();   // all K reads done before next tile's staging reuses buf 0

        // partial epilogue: o (bf16) and l (f32) per (sp, bh, qt)
        const size_t obase = (((size_t)sp * 1024 + (size_t)bh * 32 + qt) * 4096);
        const size_t lbase = (((size_t)sp * 1024 + (size_t)bh * 32 + qt) * 64);
        float lsum[4];
#pragma unroll
        for (int reg = 0; reg < 4; reg++) {
            float v = rsl[reg];
#pragma unroll
            for (int off = 1; off < 16; off <<= 1)
                v += __shfl_xor(v, off);
            lsum[reg] = v;
        }
        if (c16 == 0) {
#pragma unroll
            for (int reg = 0; reg < 4; reg++)
                Lp[lbase + wave * 16 + quad * 4 + reg] = lsum[reg];
        }
#pragma unroll
        for (int dt = 0; dt < 4; dt++)
#pragma unroll
            for (int reg = 0; reg < 4; reg++) {
                int row = wave * 16 + quad * 4 + reg;
                int d = dt * 16 + c16;
                Op[obase + row * 64 + d] = bf16rne(o[dt][reg]);
            }
    }
}

// ---------------- Kernel 3: combine ksplit partials ----------------
__global__ __launch_bounds__(256) void combine(
    const u16* __restrict__ Op, const float* __restrict__ Lp,
    float* __restrict__ Out)
{
    const int i = blockIdx.x * 256 + threadIdx.x;   // 1048576 threads, 4 floats each
    const size_t lin = (size_t)i * 4;
    const int d  = (int)(lin & 1023);
    const int h  = d >> 6, dd = d & 63;
    const int l  = (int)((lin >> 10) & 2047);
    const int b  = (int)(lin >> 21);
    const int qt = l >> 6, row = l & 63;
    const int bh = b * 16 + h;
    const size_t o0 = (((size_t)bh * 32 + qt) * 4096) + row * 64 + dd;
    const size_t o1 = o0 + (size_t)1024 * 4096;
    const size_t l0 = (((size_t)bh * 32 + qt) * 64) + row;
    ushort4 pa = *(const ushort4*)&Op[o0];
    ushort4 pb = *(const ushort4*)&Op[o1];
    float inv = __builtin_amdgcn_rcpf(Lp[l0] + Lp[l0 + 65536]);
    float4 r;
    r.x = (bf16f(pa.x) + bf16f(pb.x)) * inv;
    r.y = (bf16f(pa.y) + bf16f(pb.y)) * inv;
    r.z = (bf16f(pa.z) + bf16f(pb.z)) * inv;
    r.w = (bf16f(pa.w) + bf16f(pb.w)) * inv;
    *(float4*)&Out[lin] = r;
}

extern "C" void kernel_launch(void* const* d_in, const int* in_sizes, int n_in,
                              void* d_out, int out_size, void* d_ws, size_t ws_size,
                              hipStream_t stream) {
    const float* X  = (const float*)d_in[0];
    const int*   AM = (const int*)d_in[1];
    const float* Wq = (const float*)d_in[2];
    const float* Wk = (const float*)d_in[3];
    const float* Wv = (const float*)d_in[4];
    float* out = (float*)d_out;

    const size_t NE = (size_t)2 * 16 * 2048 * 64;   // 4.19M elems
    const size_t WN = (size_t)1024 * 1024;
    u16* Qh  = (u16*)d_ws;
    u16* Ql  = Qh + NE;
    u16* Kh  = Ql + NE;
    u16* Kl  = Kh + NE;
    u16* VT  = Kl + NE;
    u16* Xh  = VT + NE;      // Xh..Wql dead after qkv_gemm -> reused as Op
    u16* Xl  = Xh + NE;
    u16* Wqh = Xl + NE;
    u16* Wql = Wqh + WN;
    u16* Wkh = Wql + WN;
    u16* Wkl = Wkh + WN;
    u16* Wvh = Wkl + WN;     // ~69.2 MB total
    u16*   Op = Xh;
    float* Lp = (float*)Wkh;

    presplit<<<7168, 256, 0, stream>>>(X, Wq, Wk, Wv, Xh, Xl, Wqh, Wql, Wkh, Wkl, Wvh);
    qkv_gemm<<<768, 256, 0, stream>>>(Xh, Xl, Wqh, Wql, Wkh, Wkl, Wvh,
                                      Qh, Ql, Kh, Kl, VT);
    attn<<<dim3(32, 16, 2), 256, 0, stream>>>(Qh, Ql, Kh, Kl, VT, AM, Op, Lp);
    combine<<<4096, 256, 0, stream>>>(Op, Lp, out);
}